// Round 6
// baseline (385.738 us; speedup 1.0000x reference)
//
#include <hip/hip_runtime.h>
#include <hip/hip_bf16.h>
#include <cstdint>

// Problem constants
#define BB 512      // batch
#define TT 128      // time steps
#define VV 50000
#define DD 300      // embed dim
#define HH 512      // hidden
#define MLPD 1024
#define CC 3

typedef __bf16 bf16x8 __attribute__((ext_vector_type(8)));
typedef float  f32x4  __attribute__((ext_vector_type(4)));
typedef int    v8i    __attribute__((ext_vector_type(8)));

struct alignas(8)  bf4 { __bf16 x, y, z, w; };

// scaled fast tanh: 16*tanh(x) = 16 - 32/(exp(2x)+1). Saturates at +/-16.
__device__ __forceinline__ float ftanh16(float x) {
    float e = __expf(2.0f * x);
    return 16.0f - 32.0f * __builtin_amdgcn_rcpf(e + 1.0f);
}

// e8m0 scale bytes: value = 2^(E-127). h stored x16 -> scale 2^-4 (E=123).
// W stored x8 -> scale 2^-3 (E=124).
#define SCALE_H 0x7B7B7B7B
#define SCALE_W 0x7C7C7C7C

// ---------------------------------------------------------------------------
// k_prep_hh8: W_hh (fp32 [c][k]) -> fp8 e4m3 (x8) in MFMA frag order for
// 16x16x128: frag F = ((w*4+ct)*4+kch)*64 + lane (32 B each);
// lane = n + 16q holds W[c = w*64+ct*16+n][k = kch*128 + q*32 + j], j=0..31.
// (Used as the A-operand in k_rnn's swapped MFMA.)
// ---------------------------------------------------------------------------
__global__ __launch_bounds__(256) void k_prep_hh8(
    const float* __restrict__ W, unsigned char* __restrict__ out)
{
    const int T = blockIdx.x * 256 + threadIdx.x;    // 0..8191
    const int lane = T & 63;
    const int kch = (T >> 6) & 3;
    const int ct  = (T >> 8) & 3;
    const int w   = (T >> 10) & 7;
    const int n = lane & 15, q = lane >> 4;
    const int c  = w * 64 + ct * 16 + n;
    const int k0 = kch * 128 + q * 32;
    const float* src = W + c * HH + k0;
    unsigned int wd[8];
    #pragma unroll
    for (int i = 0; i < 8; ++i) {
        float4 v = *(const float4*)(src + i * 4);
        unsigned int t0 = __builtin_amdgcn_cvt_pk_fp8_f32(v.x * 8.f, v.y * 8.f, 0, false);
        t0 = __builtin_amdgcn_cvt_pk_fp8_f32(v.z * 8.f, v.w * 8.f, t0, true);
        wd[i] = t0;
    }
    *(uint4*)(out + (size_t)T * 32)      = make_uint4(wd[0], wd[1], wd[2], wd[3]);
    *(uint4*)(out + (size_t)T * 32 + 16) = make_uint4(wd[4], wd[5], wd[6], wd[7]);
}

// ---------------------------------------------------------------------------
// k_prep_ih: W_ih (fp32 [c][k], K=300 zero-padded to 320) -> bf16 B-frag
// order, 32 col-tiles of 16: b128 #U = (g*10+kc)*64 + lane;
// c = g*16 + (lane&15), k = kc*32 + (lane>>4)*8.
// ---------------------------------------------------------------------------
__global__ __launch_bounds__(256) void k_prep_ih(
    const float* __restrict__ W, __bf16* __restrict__ out)
{
    const int U = blockIdx.x * 256 + threadIdx.x;    // 0..20479
    const int lane = U & 63;
    const int rest = U >> 6;
    const int kc = rest % 10;
    const int g  = rest / 10;                        // 0..31
    const int c = g * 16 + (lane & 15);
    const int k = kc * 32 + (lane >> 4) * 8;
    bf16x8 o;
    #pragma unroll
    for (int j = 0; j < 8; ++j) {
        const int kk = k + j;
        o[j] = (__bf16)((kk < DD) ? W[c * DD + kk] : 0.f);
    }
    *(bf16x8*)(out + (size_t)U * 8) = o;
}

// ---------------------------------------------------------------------------
// k_proj: P_c[t] = C-frag-ordered (E[x[i,T-1-t]] @ W_ih^T + b_ih + b_hh).
// Grid (128 t, 8 i-tiles) x 256 thr (4 waves). LOW-PRESSURE version: each
// wave owns 16 rows (Af[10] = 40 VGPRs) and loops 32 col-tiles of 16
// (Bf[10] streamed from L2). ~115 VGPRs total -> no spill.
// P_c flat bf16 index: ((t*32 + wgt)*8 + (nt>>2))*1024 + lane*16 + (nt&3)*4 + r
//   holds value for sample row q*4+r (lane = n+16q) and col nt*16+n.
// ---------------------------------------------------------------------------
__global__ __launch_bounds__(256, 3) void k_proj(
    const int* __restrict__ x, const int* __restrict__ lengths,
    const float* __restrict__ E, const __bf16* __restrict__ Wih,
    const float* __restrict__ b_ih, const float* __restrict__ b_hh,
    __bf16* __restrict__ P_c)
{
    __shared__ __bf16 Afs[4][10 * 64 * 8];   // 10 KB per wave
    __shared__ float bias_s[HH];

    const int t   = blockIdx.x;
    const int i0  = blockIdx.y * 64;
    const int wg0 = blockIdx.y * 4;
    const int tid = threadIdx.x;
    const int wv = tid >> 6, lane = tid & 63;
    const int thr = TT - 1 - t;

    bias_s[tid]       = b_ih[tid]       + b_hh[tid];
    bias_s[tid + 256] = b_ih[tid + 256] + b_hh[tid + 256];

    // ---- coalesced gather: this wave's 16 rows into A-frag LDS ----
    {
        const int k0a = lane * 4;                       // 0..252
        const int cha = k0a >> 5, ga = (k0a >> 3) & 3;
        const int k0b = 256 + lane * 4;                 // 256..316 (lanes 0..15)
        const int chb = k0b >> 5, gb = (k0b >> 3) & 3;
        #pragma unroll 4
        for (int rl = 0; rl < 16; ++rl) {
            const int gr = i0 + wv * 16 + rl;
            const bool act = thr < lengths[gr];          // wave-uniform
            float4 v0 = make_float4(0.f, 0.f, 0.f, 0.f);
            float4 v1 = make_float4(0.f, 0.f, 0.f, 0.f);
            if (act) {
                const float* erow = E + (size_t)x[gr * TT + thr] * DD;
                v0 = *(const float4*)(erow + k0a);
                if (lane < 11) v1 = *(const float4*)(erow + k0b);
            }
            bf4 p0 = {(__bf16)v0.x, (__bf16)v0.y, (__bf16)v0.z, (__bf16)v0.w};
            *(bf4*)(&Afs[wv][((cha * 64) + rl + 16 * ga) * 8 + (k0a & 7)]) = p0;
            if (lane < 16) {
                bf4 p1 = {(__bf16)v1.x, (__bf16)v1.y, (__bf16)v1.z, (__bf16)v1.w};
                *(bf4*)(&Afs[wv][((chb * 64) + rl + 16 * gb) * 8 + (k0b & 7)]) = p1;
            }
        }
    }
    __syncthreads();

    bf16x8 Af[10];
    #pragma unroll
    for (int kc = 0; kc < 10; ++kc)
        Af[kc] = *(const bf16x8*)(&Afs[wv][(kc * 64 + lane) * 8]);

    for (int nt = 0; nt < 32; ++nt) {
        const __bf16* bbase = Wih + ((size_t)(nt * 10) * 64 + lane) * 8;
        bf16x8 Bf[10];
        #pragma unroll
        for (int kc = 0; kc < 10; ++kc)
            Bf[kc] = *(const bf16x8*)(bbase + (size_t)kc * 512);

        f32x4 acc = {};
        #pragma unroll
        for (int kc = 0; kc < 10; ++kc)
            acc = __builtin_amdgcn_mfma_f32_16x16x32_bf16(Af[kc], Bf[kc], acc, 0, 0, 0);

        const float bias = bias_s[nt * 16 + (lane & 15)];
        bf4 pk = {(__bf16)(acc[0] + bias), (__bf16)(acc[1] + bias),
                  (__bf16)(acc[2] + bias), (__bf16)(acc[3] + bias)};
        const size_t off = ((size_t)((t * 32 + wg0 + wv) * 8 + (nt >> 2))) * 1024
                         + lane * 16 + (nt & 3) * 4;
        *(bf4*)(P_c + off) = pk;
    }
}

// ---------------------------------------------------------------------------
// k_rnn: fp8-MX recurrence, OPERAND-SWAPPED (W = A operand, h = B operand).
// 32 WGs x 512 thr (8 waves, 2/SIMD). C/D lane n+16q now holds sample m=n,
// hidden cols c = w*64 + ct*16 + q*4 + r -> 4 consecutive fp8 bytes per ct
// => epilogue is 4 packed ds_write_b32 (vs 16 b8), carry predicate is
// lane-uniform. P read as 16 scalar bf16 loads, double-buffered 1 step
// ahead. Hs double-buffered A/B-frag layout (identical lane mapping), 1
// barrier/step. ftanh16 folds the x16 fp8 scale.
// ---------------------------------------------------------------------------
__global__ __launch_bounds__(512, 2) void k_rnn(
    const int* __restrict__ lengths, const unsigned char* __restrict__ Wb8,
    const __bf16* __restrict__ P_c, __bf16* __restrict__ h_final)
{
    __shared__ unsigned char Hs8[2][8192];

    const int tid = threadIdx.x;
    const int wg  = blockIdx.x;
    const int r0  = wg * 16;
    const int w    = tid >> 6;
    const int lane = tid & 63;
    const int n = lane & 15, q = lane >> 4;

    // zero buffer 0 (read at t=0)
    for (int i = tid * 16; i < 8192; i += 512 * 16)
        *(uint4*)(&Hs8[0][i]) = make_uint4(0u, 0u, 0u, 0u);

    const int len_n = lengths[r0 + n];    // this lane's sample row

    // whole 64-col W slice -> registers (128 VGPRs), frag order
    v8i Wv[4][4];
    #pragma unroll
    for (int ct = 0; ct < 4; ++ct)
        #pragma unroll
        for (int kch = 0; kch < 4; ++kch)
            Wv[ct][kch] = *(const v8i*)(Wb8 + ((size_t)(((w * 4 + ct) * 4 + kch) * 64 + lane)) * 32);

    // epilogue word addresses (t-invariant): c = w*64 + ct*16 + q*4 (+r)
    int waddr[4];
    #pragma unroll
    for (int ct = 0; ct < 4; ++ct)
        waddr[ct] = ((w >> 1) * 64 + n + 16 * ((2 * w + (ct >> 1)) & 3)) * 32
                  + (ct & 1) * 16 + q * 4;

    // per-lane P base: block + (q*4 + 16*(n>>2))*16 + (n&3)
    const int pboff = (q * 4 + 16 * (n >> 2)) * 16 + (n & 3);

    float hold[4][4] = {};    // 16*h for this lane's (row n, 16 cols); carry regs

    __syncthreads();

    // preload P for t=0
    __bf16 pv[4][4];
    {
        const __bf16* pl = P_c + ((size_t)((0 * 32 + wg) * 8 + w)) * 1024 + pboff;
        #pragma unroll
        for (int ct = 0; ct < 4; ++ct)
            #pragma unroll
            for (int r = 0; r < 4; ++r)
                pv[ct][r] = pl[r * 16 + ct * 4];
    }

    for (int t = 0; t < TT; ++t) {
        const unsigned char* rbuf = Hs8[t & 1];
        unsigned char*       wbuf = Hs8[(t + 1) & 1];

        f32x4 acc[4] = {};
        #pragma unroll
        for (int kch = 0; kch < 4; ++kch) {
            v8i hfrag = *(const v8i*)(&rbuf[(kch * 64 + lane) * 32]);
            acc[0] = __builtin_amdgcn_mfma_scale_f32_16x16x128_f8f6f4(
                         Wv[0][kch], hfrag, acc[0], 0, 0, 0, SCALE_W, 0, SCALE_H);
            acc[1] = __builtin_amdgcn_mfma_scale_f32_16x16x128_f8f6f4(
                         Wv[1][kch], hfrag, acc[1], 0, 0, 0, SCALE_W, 0, SCALE_H);
            acc[2] = __builtin_amdgcn_mfma_scale_f32_16x16x128_f8f6f4(
                         Wv[2][kch], hfrag, acc[2], 0, 0, 0, SCALE_W, 0, SCALE_H);
            acc[3] = __builtin_amdgcn_mfma_scale_f32_16x16x128_f8f6f4(
                         Wv[3][kch], hfrag, acc[3], 0, 0, 0, SCALE_W, 0, SCALE_H);
        }

        // prefetch next step's P while MFMA completes
        __bf16 pnx[4][4];
        {
            const int tn = (t + 1 < TT) ? t + 1 : t;
            const __bf16* pl = P_c + ((size_t)((tn * 32 + wg) * 8 + w)) * 1024 + pboff;
            #pragma unroll
            for (int ct = 0; ct < 4; ++ct)
                #pragma unroll
                for (int r = 0; r < 4; ++r)
                    pnx[ct][r] = pl[r * 16 + ct * 4];
        }

        const bool act = (TT - 1 - t) < len_n;   // lane-uniform row activity
        #pragma unroll
        for (int ct = 0; ct < 4; ++ct) {
            #pragma unroll
            for (int r = 0; r < 4; ++r) {
                const float th = ftanh16(acc[ct][r] + (float)pv[ct][r]);
                hold[ct][r] = act ? th : hold[ct][r];
            }
            unsigned int pw = __builtin_amdgcn_cvt_pk_fp8_f32(hold[ct][0], hold[ct][1], 0u, false);
            pw = __builtin_amdgcn_cvt_pk_fp8_f32(hold[ct][2], hold[ct][3], pw, true);
            *(unsigned int*)(&wbuf[waddr[ct]]) = pw;
        }
        #pragma unroll
        for (int ct = 0; ct < 4; ++ct)
            #pragma unroll
            for (int r = 0; r < 4; ++r)
                pv[ct][r] = pnx[ct][r];

        __syncthreads();   // wbuf complete before next step reads it
    }

    // drain: final h in Hs8[0]. fp8 frag -> bf16 rows (x 1/16).
    {
        const int half   = tid & 1;
        const int lane_t = (tid >> 1) & 63;
        const int kch    = tid >> 7;
        const int m  = lane_t & 15, qq = lane_t >> 4;
        const int cb = kch * 128 + qq * 32 + half * 16;
        uint4 wv4 = *(const uint4*)(&Hs8[0][(kch * 64 + lane_t) * 32 + half * 16]);
        unsigned int ws4[4] = {wv4.x, wv4.y, wv4.z, wv4.w};
        bf16x8 o0, o1;
        #pragma unroll
        for (int wd = 0; wd < 4; ++wd) {
            float f0 = __builtin_amdgcn_cvt_f32_fp8(ws4[wd], 0) * 0.0625f;
            float f1 = __builtin_amdgcn_cvt_f32_fp8(ws4[wd], 1) * 0.0625f;
            float f2 = __builtin_amdgcn_cvt_f32_fp8(ws4[wd], 2) * 0.0625f;
            float f3 = __builtin_amdgcn_cvt_f32_fp8(ws4[wd], 3) * 0.0625f;
            if (wd < 2) {
                o0[wd * 4 + 0] = (__bf16)f0; o0[wd * 4 + 1] = (__bf16)f1;
                o0[wd * 4 + 2] = (__bf16)f2; o0[wd * 4 + 3] = (__bf16)f3;
            } else {
                o1[(wd - 2) * 4 + 0] = (__bf16)f0; o1[(wd - 2) * 4 + 1] = (__bf16)f1;
                o1[(wd - 2) * 4 + 2] = (__bf16)f2; o1[(wd - 2) * 4 + 3] = (__bf16)f3;
            }
        }
        *(bf16x8*)(h_final + (size_t)(r0 + m) * HH + cb)     = o0;
        *(bf16x8*)(h_final + (size_t)(r0 + m) * HH + cb + 8) = o1;
    }
}

// ---------------------------------------------------------------------------
// k_mlp: a = relu(h @ l0_w^T + l0_b), fp32 out. 64x64 tiles, K=512.
// ---------------------------------------------------------------------------
#define LKH 520

__global__ __launch_bounds__(256) void k_mlp(
    const __bf16* __restrict__ hfin, const float* __restrict__ l0_w,
    const float* __restrict__ l0_b, float* __restrict__ a_buf)
{
    __shared__ __bf16 As[64 * LKH];
    __shared__ __bf16 Bs[64 * LKH];
    const int i0  = blockIdx.y * 64;
    const int n0  = blockIdx.x * 64;
    const int tid = threadIdx.x;

    {
        const int row = tid >> 2, kq = tid & 3;
        const __bf16* asrc = hfin + (i0 + row) * HH + kq * 128;
        __bf16* adst = &As[row * LKH + kq * 128];
        #pragma unroll
        for (int j = 0; j < 128; j += 8)
            *(uint4*)(adst + j) = *(const uint4*)(asrc + j);
        const float* bsrc = l0_w + (n0 + row) * HH + kq * 128;
        __bf16* bdst = &Bs[row * LKH + kq * 128];
        #pragma unroll
        for (int j = 0; j < 128; j += 4) {
            float4 v = *(const float4*)(bsrc + j);
            bf4 pk = {(__bf16)v.x, (__bf16)v.y, (__bf16)v.z, (__bf16)v.w};
            *(bf4*)(bdst + j) = pk;
        }
    }
    __syncthreads();

    const int wave = tid >> 6, lane = tid & 63;
    const int wm = (wave & 1) * 32, wn = (wave >> 1) * 32;
    const int lr = lane & 15, kk = (lane >> 4) * 8;
    f32x4 acc[2][2] = {};
    #pragma unroll
    for (int kc = 0; kc < 16; ++kc) {
        const int kb = kc * 32 + kk;
        bf16x8 a0 = *(const bf16x8*)(&As[(wm      + lr) * LKH + kb]);
        bf16x8 a1 = *(const bf16x8*)(&As[(wm + 16 + lr) * LKH + kb]);
        bf16x8 b0 = *(const bf16x8*)(&Bs[(wn      + lr) * LKH + kb]);
        bf16x8 b1 = *(const bf16x8*)(&Bs[(wn + 16 + lr) * LKH + kb]);
        acc[0][0] = __builtin_amdgcn_mfma_f32_16x16x32_bf16(a0, b0, acc[0][0], 0, 0, 0);
        acc[0][1] = __builtin_amdgcn_mfma_f32_16x16x32_bf16(a0, b1, acc[0][1], 0, 0, 0);
        acc[1][0] = __builtin_amdgcn_mfma_f32_16x16x32_bf16(a1, b0, acc[1][0], 0, 0, 0);
        acc[1][1] = __builtin_amdgcn_mfma_f32_16x16x32_bf16(a1, b1, acc[1][1], 0, 0, 0);
    }

    const int mrow = (lane >> 4) * 4, ncol = lane & 15;
    #pragma unroll
    for (int ni = 0; ni < 2; ++ni) {
        const int nl = wn + ni * 16 + ncol;
        const float bias = l0_b[n0 + nl];
        #pragma unroll
        for (int mi = 0; mi < 2; ++mi) {
            #pragma unroll
            for (int r = 0; r < 4; ++r) {
                const int ml = wm + mi * 16 + mrow + r;
                a_buf[(i0 + ml) * MLPD + (n0 + nl)] = fmaxf(acc[mi][ni][r] + bias, 0.f);
            }
        }
    }
}

// ---------------------------------------------------------------------------
// k_out: logits = relu(a @ l1_w^T + l1_b); out = log_softmax(logits).
// ---------------------------------------------------------------------------
__global__ __launch_bounds__(256) void k_out(
    const float* __restrict__ a_buf, const float* __restrict__ l1_w,
    const float* __restrict__ l1_b, float* __restrict__ out)
{
    __shared__ float red[32][8][3];
    const int tid = threadIdx.x;
    const int r = tid >> 3, p = tid & 7;
    const int row = blockIdx.x * 32 + r;
    const float* arow = a_buf + row * MLPD + p * 128;
    float pl0 = 0.f, pl1 = 0.f, pl2 = 0.f;
    #pragma unroll 8
    for (int j = 0; j < 128; j += 4) {
        float4 av = *(const float4*)(arow + j);
        float4 w0 = *(const float4*)(l1_w + 0 * MLPD + p * 128 + j);
        float4 w1 = *(const float4*)(l1_w + 1 * MLPD + p * 128 + j);
        float4 w2 = *(const float4*)(l1_w + 2 * MLPD + p * 128 + j);
        pl0 += av.x * w0.x + av.y * w0.y + av.z * w0.z + av.w * w0.w;
        pl1 += av.x * w1.x + av.y * w1.y + av.z * w1.z + av.w * w1.w;
        pl2 += av.x * w2.x + av.y * w2.y + av.z * w2.z + av.w * w2.w;
    }
    red[r][p][0] = pl0; red[r][p][1] = pl1; red[r][p][2] = pl2;
    __syncthreads();
    if (p == 0) {
        float l[3];
        #pragma unroll
        for (int c = 0; c < 3; ++c) {
            float s = 0.f;
            #pragma unroll
            for (int qq = 0; qq < 8; ++qq) s += red[r][qq][c];
            s += l1_b[c];
            l[c] = fmaxf(s, 0.f);
        }
        float m = fmaxf(l[0], fmaxf(l[1], l[2]));
        float sum = expf(l[0] - m) + expf(l[1] - m) + expf(l[2] - m);
        float ls = m + logf(sum);
        out[row * CC + 0] = l[0] - ls;
        out[row * CC + 1] = l[1] - ls;
        out[row * CC + 2] = l[2] - ls;
    }
}

// ---------------------------------------------------------------------------
extern "C" void kernel_launch(void* const* d_in, const int* in_sizes, int n_in,
                              void* d_out, int out_size, void* d_ws, size_t ws_size,
                              hipStream_t stream) {
    const int*   x    = (const int*)  d_in[0];
    const int*   len  = (const int*)  d_in[1];
    const float* E    = (const float*)d_in[2];
    const float* W_ih = (const float*)d_in[3];
    const float* b_ih = (const float*)d_in[4];
    const float* W_hh = (const float*)d_in[5];
    const float* b_hh = (const float*)d_in[6];
    const float* l0_w = (const float*)d_in[7];
    const float* l0_b = (const float*)d_in[8];
    const float* l1_w = (const float*)d_in[9];
    const float* l1_b = (const float*)d_in[10];
    float* out = (float*)d_out;

    char* ws = (char*)d_ws;
    // layout: Wb8 fp8 @0 (256KB); Wih_frag @512KB (320KB); h_final @1MB
    // (512KB); P_c @2MB (64MiB); a_buf @2MB+64MiB (2MB). ~69MB total.
    unsigned char* Wb8 = (unsigned char*)ws;
    __bf16* Wih   = (__bf16*)(ws + 524288);
    __bf16* hfin  = (__bf16*)(ws + 1048576);
    __bf16* P_c   = (__bf16*)(ws + 2097152);
    float*  a_buf = (float*) (ws + 2097152 + 67108864ull);

    k_prep_hh8<<<32, 256, 0, stream>>>(W_hh, Wb8);
    k_prep_ih<<<80, 256, 0, stream>>>(W_ih, Wih);
    dim3 g1(128, 8);
    k_proj<<<g1, 256, 0, stream>>>(x, len, E, Wih, b_ih, b_hh, P_c);
    k_rnn<<<32, 512, 0, stream>>>(len, Wb8, P_c, hfin);
    dim3 g3(16, 8);
    k_mlp<<<g3, 256, 0, stream>>>(hfin, l0_w, l0_b, a_buf);
    k_out<<<16, 256, 0, stream>>>(a_buf, l1_w, l1_b, out);
}